// Round 2
// baseline (13966.771 us; speedup 1.0000x reference)
//
#include <hip/hip_runtime.h>
#include <hip/hip_bf16.h>
#include <stdint.h>

#define NN 100000
#define NE 1600000

typedef unsigned int u32;
typedef unsigned short u16;

__device__ __forceinline__ float bf2f(u16 u) {
    return __uint_as_float(((u32)u) << 16);
}
__device__ __forceinline__ u16 f2bf(float f) {
    u32 u = __float_as_uint(f);
    u = u + 0x7FFFu + ((u >> 16) & 1u);
    return (u16)(u >> 16);
}

// ---------------- dtype detection ----------------
// flags[0]: edge_index is int64. flags[1]: float tensors are bf16.
// bf16 test: dword bits14..7 is the low-element exponent field if data is
// bf16 pairs (N(0,1) values => field in [96,160] or 0); if data is fp32,
// those bits are mid-mantissa (uniform over 0..255).
__global__ void detect_kernel(const u32* __restrict__ ei,
                              const u32* __restrict__ x, int* flags) {
    __shared__ int bad64, badbf;
    int t = threadIdx.x;
    if (t == 0) { bad64 = 0; badbf = 0; }
    __syncthreads();
    if (ei[2 * t + 1] != 0u) atomicAdd(&bad64, 1);
    u32 d = x[t];
    u32 e = (d >> 7) & 0xFFu;
    if (e != 0u && (e < 96u || e > 160u)) atomicAdd(&badbf, 1);
    __syncthreads();
    if (t == 0) {
        flags[0] = (bad64 < 16) ? 1 : 0;
        flags[1] = (badbf < 16) ? 1 : 0;
    }
}

__device__ __forceinline__ void load_edge(const void* ei, int e, int is64,
                                          int& s, int& d) {
    if (is64) {
        const long long* p = (const long long*)ei;
        s = (int)p[e];
        d = (int)p[NE + e];
    } else {
        const int* p = (const int*)ei;
        s = p[e];
        d = p[NE + e];
    }
}

// ---------------- CSR build ----------------
__global__ void zero_counts(int* counts) {
    int i = blockIdx.x * 256 + threadIdx.x;
    if (i < NN) counts[i] = 0;
}

__global__ void count_deg(const void* ei, const int* __restrict__ flags,
                          int* __restrict__ counts) {
    int e = blockIdx.x * 256 + threadIdx.x;
    if (e >= NE) return;
    int s, d;
    load_edge(ei, e, flags[0], s, d);
    atomicAdd(&counts[d], 1);
}

__global__ void scan_block(const int* __restrict__ counts,
                           int* __restrict__ off, int* __restrict__ bsums) {
    __shared__ int sS[256];
    int t = threadIdx.x;
    int base = blockIdx.x * 1024 + t * 4;
    int c[4];
#pragma unroll
    for (int i = 0; i < 4; ++i) c[i] = (base + i < NN) ? counts[base + i] : 0;
    int s = c[0] + c[1] + c[2] + c[3];
    sS[t] = s;
    __syncthreads();
    for (int dlt = 1; dlt < 256; dlt <<= 1) {
        int v = (t >= dlt) ? sS[t - dlt] : 0;
        __syncthreads();
        sS[t] += v;
        __syncthreads();
    }
    int run = sS[t] - s;
    if (t == 255) bsums[blockIdx.x] = sS[255];
#pragma unroll
    for (int i = 0; i < 4; ++i) {
        if (base + i < NN) off[base + i] = run;
        run += c[i];
    }
}

__global__ void scan_top(int* bsums, int nb) {
    if (threadIdx.x == 0 && blockIdx.x == 0) {
        int run = 0;
        for (int i = 0; i < nb; ++i) {
            int v = bsums[i];
            bsums[i] = run;
            run += v;
        }
    }
}

__global__ void scan_add(int* __restrict__ off, const int* __restrict__ bsums,
                         int* __restrict__ cursor) {
    int i = blockIdx.x * 256 + threadIdx.x;
    if (i < NN) {
        int v = off[i] + bsums[i >> 10];
        off[i] = v;
        cursor[i] = v;
    }
    if (i == 0) off[NN] = NE;
}

__global__ void fill_csr(const void* ei, const int* __restrict__ flags,
                         int* __restrict__ cursor, int* __restrict__ ssrc) {
    int e = blockIdx.x * 256 + threadIdx.x;
    if (e >= NE) return;
    int s, d;
    load_edge(ei, e, flags[0], s, d);
    int pos = atomicAdd(&cursor[d], 1);
    ssrc[pos] = s;
}

// ---------------- mean aggregation (gather, no atomics) ----------------
// one wave per node; lane owns 2 channels; intermediates always fp32
__global__ __launch_bounds__(256) void gather_mean(
    const void* __restrict__ feat, int feat_maybe_bf,
    const int* __restrict__ flags, const int* __restrict__ off,
    const int* __restrict__ ssrc, float* __restrict__ meanF) {
    int node = blockIdx.x * 4 + (threadIdx.x >> 6);
    int lane = threadIdx.x & 63;
    int o0 = off[node], o1 = off[node + 1];
    float a0 = 0.f, a1 = 0.f;
    if (feat_maybe_bf && flags[1]) {
        const u32* f = (const u32*)feat;
        for (int j = o0; j < o1; ++j) {
            int idx = ssrc[j];
            u32 u = f[(size_t)idx * 64 + lane];
            a0 += __uint_as_float(u << 16);
            a1 += __uint_as_float(u & 0xFFFF0000u);
        }
    } else {
        const float2* f = (const float2*)feat;
        for (int j = o0; j < o1; ++j) {
            int idx = ssrc[j];
            float2 v = f[(size_t)idx * 64 + lane];
            a0 += v.x;
            a1 += v.y;
        }
    }
    int deg = o1 - o0;
    float inv = 1.0f / (float)(deg > 0 ? deg : 1);
    ((float2*)meanF)[(size_t)node * 64 + lane] = make_float2(a0 * inv, a1 * inv);
}

// ---------------- fused linear: out = [self|mean] @ [Wr;Wl] + b ----------------
// fp32 compute; W staged to LDS as fp32; self maybe bf16, mean always fp32.
template <int COUT, int ROWS, bool RELU>
__global__ __launch_bounds__(256, 2) void sage_linear(
    const void* __restrict__ selfF, int self_maybe_bf,
    const float* __restrict__ meanF, const void* __restrict__ Wr,
    const void* __restrict__ Wl, const void* __restrict__ bias,
    void* __restrict__ out, int out_final, const int* __restrict__ flags) {
    constexpr int BX = COUT / 4;
    constexpr int BY = 256 / BX;
    constexpr int RPT = ROWS / BY;
    __shared__ __align__(16) float sA[ROWS * 256];
    __shared__ __align__(16) float sW[128 * COUT];

    const int tid = threadIdx.x;
    const int tx = tid % BX;
    const int ty = tid / BX;
    const int row0 = blockIdx.x * ROWS;
    const int bfin = flags[1];
    const int selfbf = self_maybe_bf && bfin;

    // stage A rows as fp32: cols 0..127 = self, 128..255 = mean
    for (int i = tid; i < ROWS * 128; i += 256) {
        int r = i >> 7;
        int kp = i & 127;
        int n = row0 + r;
        float2 v = make_float2(0.f, 0.f);
        if (n < NN) {
            if (kp < 64) {
                if (selfbf) {
                    u32 u = ((const u32*)selfF)[(size_t)n * 64 + kp];
                    v.x = __uint_as_float(u << 16);
                    v.y = __uint_as_float(u & 0xFFFF0000u);
                } else {
                    v = ((const float2*)selfF)[(size_t)n * 64 + kp];
                }
            } else {
                v = ((const float2*)meanF)[(size_t)n * 64 + (kp - 64)];
            }
        }
        *(float2*)&sA[r * 256 + 2 * kp] = v;
    }

    float acc[RPT][4];
    {
        float4 b;
        if (bfin) {
            ushort4 bb = ((const ushort4*)bias)[tx];
            b = make_float4(bf2f(bb.x), bf2f(bb.y), bf2f(bb.z), bf2f(bb.w));
        } else {
            b = ((const float4*)bias)[tx];
        }
#pragma unroll
        for (int i = 0; i < RPT; ++i) {
            acc[i][0] = b.x;
            acc[i][1] = b.y;
            acc[i][2] = b.z;
            acc[i][3] = b.w;
        }
    }

#pragma unroll
    for (int kc = 0; kc < 2; ++kc) {
        __syncthreads();
        {
            const void* Wsrc = kc ? Wl : Wr;
            constexpr int NV4 = 128 * COUT / 4;
            if (bfin) {
                const ushort4* s = (const ushort4*)Wsrc;
                for (int i = tid; i < NV4; i += 256) {
                    ushort4 w = s[i];
                    ((float4*)sW)[i] = make_float4(bf2f(w.x), bf2f(w.y),
                                                   bf2f(w.z), bf2f(w.w));
                }
            } else {
                const float4* s = (const float4*)Wsrc;
                for (int i = tid; i < NV4; i += 256) ((float4*)sW)[i] = s[i];
            }
        }
        __syncthreads();
        const int kb = kc * 128;
        for (int k = 0; k < 128; k += 4) {
            float4 a[RPT];
#pragma unroll
            for (int i = 0; i < RPT; ++i)
                a[i] = *(const float4*)&sA[(ty * RPT + i) * 256 + kb + k];
#pragma unroll
            for (int kk = 0; kk < 4; ++kk) {
                float4 w = ((const float4*)sW)[(k + kk) * BX + tx];
#pragma unroll
                for (int i = 0; i < RPT; ++i) {
                    float av = (kk == 0) ? a[i].x
                             : (kk == 1) ? a[i].y
                             : (kk == 2) ? a[i].z
                                         : a[i].w;
                    acc[i][0] += av * w.x;
                    acc[i][1] += av * w.y;
                    acc[i][2] += av * w.z;
                    acc[i][3] += av * w.w;
                }
            }
        }
    }

    const int obf = out_final && bfin;
#pragma unroll
    for (int i = 0; i < RPT; ++i) {
        int n = row0 + ty * RPT + i;
        if (n < NN) {
            float v0 = acc[i][0], v1 = acc[i][1], v2 = acc[i][2], v3 = acc[i][3];
            if (RELU) {
                v0 = fmaxf(v0, 0.f);
                v1 = fmaxf(v1, 0.f);
                v2 = fmaxf(v2, 0.f);
                v3 = fmaxf(v3, 0.f);
            }
            if (obf) {
                ushort4 o;
                o.x = f2bf(v0);
                o.y = f2bf(v1);
                o.z = f2bf(v2);
                o.w = f2bf(v3);
                ((ushort4*)out)[(size_t)n * BX + tx] = o;
            } else {
                ((float4*)out)[(size_t)n * BX + tx] =
                    make_float4(v0, v1, v2, v3);
            }
        }
    }
}

extern "C" void kernel_launch(void* const* d_in, const int* in_sizes, int n_in,
                              void* d_out, int out_size, void* d_ws,
                              size_t ws_size, hipStream_t stream) {
    const void* x = d_in[0];
    const void* ei = d_in[1];
    const void* Wl0 = d_in[2];
    const void* Wr0 = d_in[3];
    const void* b0 = d_in[4];
    const void* Wl1 = d_in[5];
    const void* Wr1 = d_in[6];
    const void* b1 = d_in[7];
    const void* Wl2 = d_in[8];
    const void* Wr2 = d_in[9];
    const void* b2 = d_in[10];

    char* ws = (char*)d_ws;
    size_t o = 0;
    auto alloc = [&](size_t bytes) {
        void* p = ws + o;
        o = (o + bytes + 511) & ~(size_t)511;
        return p;
    };
    int* flags = (int*)alloc(16);
    int* counts = (int*)alloc(NN * 4);
    int* off = (int*)alloc((NN + 1) * 4);
    int* bsums = (int*)alloc(128 * 4);
    int* cursor = (int*)alloc(NN * 4);
    int* ssrc = (int*)alloc((size_t)NE * 4);
    float* meanF = (float*)alloc((size_t)NN * 128 * 4);
    float* h1 = (float*)alloc((size_t)NN * 128 * 4);
    float* h2 = h1;  // safe: each linear block reads its rows to LDS pre-write

    constexpr int NB_SCAN = (NN + 1023) / 1024;  // 98

    detect_kernel<<<1, 256, 0, stream>>>((const u32*)ei, (const u32*)x, flags);
    zero_counts<<<(NN + 255) / 256, 256, 0, stream>>>(counts);
    count_deg<<<NE / 256, 256, 0, stream>>>(ei, flags, counts);
    scan_block<<<NB_SCAN, 256, 0, stream>>>(counts, off, bsums);
    scan_top<<<1, 64, 0, stream>>>(bsums, NB_SCAN);
    scan_add<<<(NN + 255) / 256, 256, 0, stream>>>(off, bsums, cursor);
    fill_csr<<<NE / 256, 256, 0, stream>>>(ei, flags, cursor, ssrc);

    // layer 0
    gather_mean<<<NN / 4, 256, 0, stream>>>(x, 1, flags, off, ssrc, meanF);
    sage_linear<128, 16, true><<<(NN + 15) / 16, 256, 0, stream>>>(
        x, 1, meanF, Wr0, Wl0, b0, h1, 0, flags);
    // layer 1
    gather_mean<<<NN / 4, 256, 0, stream>>>(h1, 0, flags, off, ssrc, meanF);
    sage_linear<128, 16, true><<<(NN + 15) / 16, 256, 0, stream>>>(
        h1, 0, meanF, Wr1, Wl1, b1, h2, 0, flags);
    // layer 2
    gather_mean<<<NN / 4, 256, 0, stream>>>(h2, 0, flags, off, ssrc, meanF);
    sage_linear<64, 32, false><<<(NN + 31) / 32, 256, 0, stream>>>(
        h2, 0, meanF, Wr2, Wl2, b2, d_out, 1, flags);
}

// Round 3
// 6536.494 us; speedup vs baseline: 2.1367x; 2.1367x over previous
//
#include <hip/hip_runtime.h>
#include <hip/hip_bf16.h>
#include <stdint.h>

#define NN 100000
#define NE 1600000

typedef unsigned int u32;
typedef unsigned short u16;

__device__ __forceinline__ float bf2f(u16 u) {
    return __uint_as_float(((u32)u) << 16);
}
__device__ __forceinline__ u16 f2bf(float f) {
    u32 u = __float_as_uint(f);
    u = u + 0x7FFFu + ((u >> 16) & 1u);
    return (u16)(u >> 16);
}
__device__ __forceinline__ float lo16(u32 u) { return __uint_as_float(u << 16); }
__device__ __forceinline__ float hi16(u32 u) {
    return __uint_as_float(u & 0xFFFF0000u);
}

// ---------------- dtype detection ----------------
__global__ void detect_kernel(const u32* __restrict__ ei,
                              const u32* __restrict__ x, int* flags) {
    __shared__ int bad64, badbf;
    int t = threadIdx.x;
    if (t == 0) { bad64 = 0; badbf = 0; }
    __syncthreads();
    if (ei[2 * t + 1] != 0u) atomicAdd(&bad64, 1);
    u32 d = x[t];
    u32 e = (d >> 7) & 0xFFu;
    if (e != 0u && (e < 96u || e > 160u)) atomicAdd(&badbf, 1);
    __syncthreads();
    if (t == 0) {
        flags[0] = (bad64 < 16) ? 1 : 0;
        flags[1] = (badbf < 16) ? 1 : 0;
    }
}

__device__ __forceinline__ void load_edge(const void* ei, int e, int is64,
                                          int& s, int& d) {
    if (is64) {
        const long long* p = (const long long*)ei;
        s = (int)p[e];
        d = (int)p[NE + e];
    } else {
        const int* p = (const int*)ei;
        s = p[e];
        d = p[NE + e];
    }
}

// ---------------- CSR build ----------------
__global__ void zero_counts(int* counts) {
    int i = blockIdx.x * 256 + threadIdx.x;
    if (i < NN) counts[i] = 0;
}

__global__ void count_deg(const void* ei, const int* __restrict__ flags,
                          int* __restrict__ counts) {
    int e = blockIdx.x * 256 + threadIdx.x;
    if (e >= NE) return;
    int s, d;
    load_edge(ei, e, flags[0], s, d);
    atomicAdd(&counts[d], 1);
}

__global__ void scan_block(const int* __restrict__ counts,
                           int* __restrict__ off, int* __restrict__ bsums) {
    __shared__ int sS[256];
    int t = threadIdx.x;
    int base = blockIdx.x * 1024 + t * 4;
    int c[4];
#pragma unroll
    for (int i = 0; i < 4; ++i) c[i] = (base + i < NN) ? counts[base + i] : 0;
    int s = c[0] + c[1] + c[2] + c[3];
    sS[t] = s;
    __syncthreads();
    for (int dlt = 1; dlt < 256; dlt <<= 1) {
        int v = (t >= dlt) ? sS[t - dlt] : 0;
        __syncthreads();
        sS[t] += v;
        __syncthreads();
    }
    int run = sS[t] - s;
    if (t == 255) bsums[blockIdx.x] = sS[255];
#pragma unroll
    for (int i = 0; i < 4; ++i) {
        if (base + i < NN) off[base + i] = run;
        run += c[i];
    }
}

__global__ void scan_top(int* bsums, int nb) {
    if (threadIdx.x == 0 && blockIdx.x == 0) {
        int run = 0;
        for (int i = 0; i < nb; ++i) {
            int v = bsums[i];
            bsums[i] = run;
            run += v;
        }
    }
}

__global__ void scan_add(int* __restrict__ off, const int* __restrict__ bsums,
                         int* __restrict__ cursor) {
    int i = blockIdx.x * 256 + threadIdx.x;
    if (i < NN) {
        int v = off[i] + bsums[i >> 10];
        off[i] = v;
        cursor[i] = v;
    }
    if (i == 0) off[NN] = NE;
}

__global__ void fill_csr(const void* ei, const int* __restrict__ flags,
                         int* __restrict__ cursor, int* __restrict__ ssrc) {
    int e = blockIdx.x * 256 + threadIdx.x;
    if (e >= NE) return;
    int s, d;
    load_edge(ei, e, flags[0], s, d);
    int pos = atomicAdd(&cursor[d], 1);
    ssrc[pos] = s;
}

// ---------------- mean aggregation (gather, no atomics) ----------------
__global__ __launch_bounds__(256) void gather_mean(
    const void* __restrict__ feat, int feat_maybe_bf,
    const int* __restrict__ flags, const int* __restrict__ off,
    const int* __restrict__ ssrc, float* __restrict__ meanF) {
    int node = blockIdx.x * 4 + (threadIdx.x >> 6);
    int lane = threadIdx.x & 63;
    int o0 = off[node], o1 = off[node + 1];
    float a0 = 0.f, a1 = 0.f;
    if (feat_maybe_bf && flags[1]) {
        const u32* f = (const u32*)feat;
        for (int j = o0; j < o1; ++j) {
            int idx = ssrc[j];
            u32 u = f[(size_t)idx * 64 + lane];
            a0 += lo16(u);
            a1 += hi16(u);
        }
    } else {
        const float2* f = (const float2*)feat;
        for (int j = o0; j < o1; ++j) {
            int idx = ssrc[j];
            float2 v = f[(size_t)idx * 64 + lane];
            a0 += v.x;
            a1 += v.y;
        }
    }
    int deg = o1 - o0;
    float inv = 1.0f / (float)(deg > 0 ? deg : 1);
    ((float2*)meanF)[(size_t)node * 64 + lane] = make_float2(a0 * inv, a1 * inv);
}

// ---------------- fused linear v3 ----------------
// out[n][c] = sum_k self[n][k]*Wr[k][c] + mean[n][k]*Wl[k][c] + b[c]
// Block: 128 rows x 32 cols. LDS: W slice [256][32] fp32 (32 KB), staged once.
// Thread: tx=tid&7 -> 4 cols, ty=tid>>3 -> rows ty+32*i (i<4). A from global
// (sequential along K, broadcast across the 8 tx lanes, L1-resident lines).
template <int COUT, bool RELU>
__global__ __launch_bounds__(256, 4) void sage_linear(
    const void* __restrict__ selfF, int self_maybe_bf,
    const float* __restrict__ meanF, const void* __restrict__ Wr,
    const void* __restrict__ Wl, const void* __restrict__ bias,
    void* __restrict__ out, int out_final, const int* __restrict__ flags) {
    constexpr int CB = 32;
    constexpr int NCB = COUT / CB;
    __shared__ __align__(16) float sW[256 * CB];

    const int tid = threadIdx.x;
    const int cb = blockIdx.x % NCB;
    const int rb = blockIdx.x / NCB;
    const int row0 = rb * 128;
    const int c0 = cb * CB;
    const int tx = tid & 7;
    const int ty = tid >> 3;
    const int bfin = flags[1];
    const int selfbf = self_maybe_bf && bfin;

    // stage W: sW[k][c] = (k<128 ? Wr : Wl)[k%128][c0+c], fp32
    if (bfin) {
        for (int i = tid; i < 256 * CB / 2; i += 256) {
            int k = i / (CB / 2);
            int c2 = i % (CB / 2);
            const u16* Wsrc = (const u16*)(k < 128 ? Wr : Wl);
            int kk = k & 127;
            u32 u = *(const u32*)&Wsrc[(size_t)kk * COUT + c0 + 2 * c2];
            sW[k * CB + 2 * c2] = lo16(u);
            sW[k * CB + 2 * c2 + 1] = hi16(u);
        }
    } else {
        for (int i = tid; i < 256 * CB; i += 256) {
            int k = i / CB;
            int c = i % CB;
            const float* Wsrc = (const float*)(k < 128 ? Wr : Wl);
            int kk = k & 127;
            sW[k * CB + c] = Wsrc[(size_t)kk * COUT + c0 + c];
        }
    }
    __syncthreads();

    float4 bv;
    if (bfin) {
        const u16* bp = (const u16*)bias + c0 + tx * 4;
        ushort4 bb = *(const ushort4*)bp;
        bv = make_float4(bf2f(bb.x), bf2f(bb.y), bf2f(bb.z), bf2f(bb.w));
    } else {
        bv = *(const float4*)((const float*)bias + c0 + tx * 4);
    }
    float acc[4][4];
#pragma unroll
    for (int i = 0; i < 4; ++i) {
        acc[i][0] = bv.x;
        acc[i][1] = bv.y;
        acc[i][2] = bv.z;
        acc[i][3] = bv.w;
    }

    int r[4], rl[4];
#pragma unroll
    for (int i = 0; i < 4; ++i) {
        r[i] = row0 + ty + 32 * i;
        rl[i] = (r[i] < NN) ? r[i] : (NN - 1);
    }

#define FMA16(kk, a0, a1, a2, a3)                                      \
    {                                                                  \
        acc[i][0] += a0 * w[kk].x;                                     \
        acc[i][1] += a0 * w[kk].y;                                     \
        acc[i][2] += a0 * w[kk].z;                                     \
        acc[i][3] += a0 * w[kk].w;                                     \
    }

    // --- self phase: k in [0,128), weights sW rows [0,128) ---
    if (selfbf) {
        const u32* A = (const u32*)selfF;
        for (int k = 0; k < 128; k += 4) {
            float4 w[4];
#pragma unroll
            for (int kk = 0; kk < 4; ++kk)
                w[kk] = *(const float4*)&sW[(k + kk) * CB + tx * 4];
#pragma unroll
            for (int i = 0; i < 4; ++i) {
                uint2 u = *(const uint2*)&A[(size_t)rl[i] * 64 + (k >> 1)];
                float a0 = lo16(u.x), a1 = hi16(u.x), a2 = lo16(u.y),
                      a3 = hi16(u.y);
#pragma unroll
                for (int q = 0; q < 4; ++q) {
                    float av = (q == 0) ? a0 : (q == 1) ? a1 : (q == 2) ? a2 : a3;
                    acc[i][0] += av * w[q].x;
                    acc[i][1] += av * w[q].y;
                    acc[i][2] += av * w[q].z;
                    acc[i][3] += av * w[q].w;
                }
            }
        }
    } else {
        const float* A = (const float*)selfF;
        for (int k = 0; k < 128; k += 4) {
            float4 w[4];
#pragma unroll
            for (int kk = 0; kk < 4; ++kk)
                w[kk] = *(const float4*)&sW[(k + kk) * CB + tx * 4];
#pragma unroll
            for (int i = 0; i < 4; ++i) {
                float4 a = *(const float4*)&A[(size_t)rl[i] * 128 + k];
#pragma unroll
                for (int q = 0; q < 4; ++q) {
                    float av = (q == 0) ? a.x : (q == 1) ? a.y : (q == 2) ? a.z
                                                                          : a.w;
                    acc[i][0] += av * w[q].x;
                    acc[i][1] += av * w[q].y;
                    acc[i][2] += av * w[q].z;
                    acc[i][3] += av * w[q].w;
                }
            }
        }
    }

    // --- mean phase: k in [0,128), weights sW rows [128,256) ---
    {
        const float* A = meanF;
        for (int k = 0; k < 128; k += 4) {
            float4 w[4];
#pragma unroll
            for (int kk = 0; kk < 4; ++kk)
                w[kk] = *(const float4*)&sW[(128 + k + kk) * CB + tx * 4];
#pragma unroll
            for (int i = 0; i < 4; ++i) {
                float4 a = *(const float4*)&A[(size_t)rl[i] * 128 + k];
#pragma unroll
                for (int q = 0; q < 4; ++q) {
                    float av = (q == 0) ? a.x : (q == 1) ? a.y : (q == 2) ? a.z
                                                                          : a.w;
                    acc[i][0] += av * w[q].x;
                    acc[i][1] += av * w[q].y;
                    acc[i][2] += av * w[q].z;
                    acc[i][3] += av * w[q].w;
                }
            }
        }
    }

    const int obf = out_final && bfin;
#pragma unroll
    for (int i = 0; i < 4; ++i) {
        if (r[i] < NN) {
            float v0 = acc[i][0], v1 = acc[i][1], v2 = acc[i][2], v3 = acc[i][3];
            if (RELU) {
                v0 = fmaxf(v0, 0.f);
                v1 = fmaxf(v1, 0.f);
                v2 = fmaxf(v2, 0.f);
                v3 = fmaxf(v3, 0.f);
            }
            if (obf) {
                ushort4 o;
                o.x = f2bf(v0);
                o.y = f2bf(v1);
                o.z = f2bf(v2);
                o.w = f2bf(v3);
                *(ushort4*)((u16*)out + (size_t)r[i] * COUT + c0 + tx * 4) = o;
            } else {
                *(float4*)((float*)out + (size_t)r[i] * COUT + c0 + tx * 4) =
                    make_float4(v0, v1, v2, v3);
            }
        }
    }
}

extern "C" void kernel_launch(void* const* d_in, const int* in_sizes, int n_in,
                              void* d_out, int out_size, void* d_ws,
                              size_t ws_size, hipStream_t stream) {
    const void* x = d_in[0];
    const void* ei = d_in[1];
    const void* Wl0 = d_in[2];
    const void* Wr0 = d_in[3];
    const void* b0 = d_in[4];
    const void* Wl1 = d_in[5];
    const void* Wr1 = d_in[6];
    const void* b1 = d_in[7];
    const void* Wl2 = d_in[8];
    const void* Wr2 = d_in[9];
    const void* b2 = d_in[10];

    char* ws = (char*)d_ws;
    size_t o = 0;
    auto alloc = [&](size_t bytes) {
        void* p = ws + o;
        o = (o + bytes + 511) & ~(size_t)511;
        return p;
    };
    int* flags = (int*)alloc(16);
    int* counts = (int*)alloc(NN * 4);
    int* off = (int*)alloc((NN + 1) * 4);
    int* bsums = (int*)alloc(128 * 4);
    int* cursor = (int*)alloc(NN * 4);
    int* ssrc = (int*)alloc((size_t)NE * 4);
    float* meanF = (float*)alloc((size_t)NN * 128 * 4);
    float* h1 = (float*)alloc((size_t)NN * 128 * 4);
    float* h2 = (float*)alloc((size_t)NN * 128 * 4);

    constexpr int NB_SCAN = (NN + 1023) / 1024;  // 98
    constexpr int RB = (NN + 127) / 128;         // 782

    detect_kernel<<<1, 256, 0, stream>>>((const u32*)ei, (const u32*)x, flags);
    zero_counts<<<(NN + 255) / 256, 256, 0, stream>>>(counts);
    count_deg<<<NE / 256, 256, 0, stream>>>(ei, flags, counts);
    scan_block<<<NB_SCAN, 256, 0, stream>>>(counts, off, bsums);
    scan_top<<<1, 64, 0, stream>>>(bsums, NB_SCAN);
    scan_add<<<(NN + 255) / 256, 256, 0, stream>>>(off, bsums, cursor);
    fill_csr<<<NE / 256, 256, 0, stream>>>(ei, flags, cursor, ssrc);

    // layer 0
    gather_mean<<<NN / 4, 256, 0, stream>>>(x, 1, flags, off, ssrc, meanF);
    sage_linear<128, true><<<RB * 4, 256, 0, stream>>>(x, 1, meanF, Wr0, Wl0,
                                                       b0, h1, 0, flags);
    // layer 1
    gather_mean<<<NN / 4, 256, 0, stream>>>(h1, 0, flags, off, ssrc, meanF);
    sage_linear<128, true><<<RB * 4, 256, 0, stream>>>(h1, 0, meanF, Wr1, Wl1,
                                                       b1, h2, 0, flags);
    // layer 2
    gather_mean<<<NN / 4, 256, 0, stream>>>(h2, 0, flags, off, ssrc, meanF);
    sage_linear<64, false><<<RB * 2, 256, 0, stream>>>(h2, 0, meanF, Wr2, Wl2,
                                                       b2, d_out, 1, flags);
}

// Round 4
// 915.382 us; speedup vs baseline: 15.2579x; 7.1407x over previous
//
#include <hip/hip_runtime.h>
#include <stdint.h>

#define NN 100000
#define NE 1600000

typedef unsigned int u32;
typedef unsigned short u16;
typedef short v8s __attribute__((ext_vector_type(8)));
typedef float v4f __attribute__((ext_vector_type(4)));

union U4S8 {
    uint4 u;
    v8s s;
};

__device__ __forceinline__ float bf2f(u16 u) {
    return __uint_as_float(((u32)u) << 16);
}
__device__ __forceinline__ u16 f2bf(float f) {
    u32 u = __float_as_uint(f);
    u = u + 0x7FFFu + ((u >> 16) & 1u);
    return (u16)(u >> 16);
}
__device__ __forceinline__ float lo16(u32 u) { return __uint_as_float(u << 16); }
__device__ __forceinline__ float hi16(u32 u) {
    return __uint_as_float(u & 0xFFFF0000u);
}

// ---------------- dtype detection ----------------
__global__ void detect_kernel(const u32* __restrict__ ei,
                              const u32* __restrict__ x, int* flags) {
    __shared__ int bad64, badbf;
    int t = threadIdx.x;
    if (t == 0) { bad64 = 0; badbf = 0; }
    __syncthreads();
    if (ei[2 * t + 1] != 0u) atomicAdd(&bad64, 1);
    u32 d = x[t];
    u32 e = (d >> 7) & 0xFFu;
    if (e != 0u && (e < 96u || e > 160u)) atomicAdd(&badbf, 1);
    __syncthreads();
    if (t == 0) {
        flags[0] = (bad64 < 16) ? 1 : 0;
        flags[1] = (badbf < 16) ? 1 : 0;
    }
}

__device__ __forceinline__ void load_edge(const void* ei, int e, int is64,
                                          int& s, int& d) {
    if (is64) {
        const long long* p = (const long long*)ei;
        s = (int)p[e];
        d = (int)p[NE + e];
    } else {
        const int* p = (const int*)ei;
        s = p[e];
        d = p[NE + e];
    }
}

// ---------------- prep: x -> bf16 ----------------
__global__ void conv_x(const void* __restrict__ x, const int* __restrict__ flags,
                       u32* __restrict__ xb) {
    int i = blockIdx.x * 256 + threadIdx.x;  // over NN*64 u32-pairs
    if (i >= NN * 64) return;
    u32 o;
    if (flags[1]) {
        o = ((const u32*)x)[i];
    } else {
        float2 v = ((const float2*)x)[i];
        o = ((u32)f2bf(v.y) << 16) | (u32)f2bf(v.x);
    }
    xb[i] = o;
}

// ---------------- prep: WT[c][k] = (k<128?Wr:Wl)[k%128][c], bias->f32 ----------
__global__ void wt_prep(const void* __restrict__ Wr, const void* __restrict__ Wl,
                        const void* __restrict__ bias,
                        const int* __restrict__ flags, int cout,
                        u16* __restrict__ WT, float* __restrict__ bias_f) {
    int t = blockIdx.x * 256 + threadIdx.x;
    if (t < 256 * cout) {
        int k = t / cout, c = t % cout;
        const void* W = (k < 128) ? Wr : Wl;
        int kk = k & 127;
        float v;
        if (flags[1])
            v = bf2f(((const u16*)W)[kk * cout + c]);
        else
            v = ((const float*)W)[kk * cout + c];
        WT[c * 256 + k] = f2bf(v);
    }
    if (t < cout) {
        bias_f[t] =
            flags[1] ? bf2f(((const u16*)bias)[t]) : ((const float*)bias)[t];
    }
}

// ---------------- CSR build ----------------
__global__ void zero_counts(int* counts) {
    int i = blockIdx.x * 256 + threadIdx.x;
    if (i < NN) counts[i] = 0;
}

__global__ void count_deg(const void* ei, const int* __restrict__ flags,
                          int* __restrict__ counts) {
    int e = blockIdx.x * 256 + threadIdx.x;
    if (e >= NE) return;
    int s, d;
    load_edge(ei, e, flags[0], s, d);
    atomicAdd(&counts[d], 1);
}

__global__ void scan_block(const int* __restrict__ counts,
                           int* __restrict__ off, int* __restrict__ bsums) {
    __shared__ int sS[256];
    int t = threadIdx.x;
    int base = blockIdx.x * 1024 + t * 4;
    int c[4];
#pragma unroll
    for (int i = 0; i < 4; ++i) c[i] = (base + i < NN) ? counts[base + i] : 0;
    int s = c[0] + c[1] + c[2] + c[3];
    sS[t] = s;
    __syncthreads();
    for (int dlt = 1; dlt < 256; dlt <<= 1) {
        int v = (t >= dlt) ? sS[t - dlt] : 0;
        __syncthreads();
        sS[t] += v;
        __syncthreads();
    }
    int run = sS[t] - s;
    if (t == 255) bsums[blockIdx.x] = sS[255];
#pragma unroll
    for (int i = 0; i < 4; ++i) {
        if (base + i < NN) off[base + i] = run;
        run += c[i];
    }
}

__global__ void scan_top(int* bsums, int nb) {
    if (threadIdx.x == 0 && blockIdx.x == 0) {
        int run = 0;
        for (int i = 0; i < nb; ++i) {
            int v = bsums[i];
            bsums[i] = run;
            run += v;
        }
    }
}

__global__ void scan_add(int* __restrict__ off, const int* __restrict__ bsums,
                         int* __restrict__ cursor) {
    int i = blockIdx.x * 256 + threadIdx.x;
    if (i < NN) {
        int v = off[i] + bsums[i >> 10];
        off[i] = v;
        cursor[i] = v;
    }
    if (i == 0) off[NN] = NE;
}

__global__ void fill_csr(const void* ei, const int* __restrict__ flags,
                         int* __restrict__ cursor, int* __restrict__ ssrc) {
    int e = blockIdx.x * 256 + threadIdx.x;
    if (e >= NE) return;
    int s, d;
    load_edge(ei, e, flags[0], s, d);
    int pos = atomicAdd(&cursor[d], 1);
    ssrc[pos] = s;
}

// ---------------- mean aggregation (gather, bf16 in/out) ----------------
__global__ __launch_bounds__(256) void gather_mean_b(
    const u32* __restrict__ feat, const int* __restrict__ off,
    const int* __restrict__ ssrc, u32* __restrict__ meanB) {
    int node = blockIdx.x * 4 + (threadIdx.x >> 6);
    int lane = threadIdx.x & 63;
    int o0 = off[node], o1 = off[node + 1];
    float a0 = 0.f, a1 = 0.f;
    for (int j = o0; j < o1; ++j) {
        int idx = ssrc[j];
        u32 u = feat[idx * 64 + lane];
        a0 += lo16(u);
        a1 += hi16(u);
    }
    int deg = o1 - o0;
    float inv = 1.0f / (float)(deg > 0 ? deg : 1);
    meanB[node * 64 + lane] =
        ((u32)f2bf(a1 * inv) << 16) | (u32)f2bf(a0 * inv);
}

// ---------------- MFMA GEMM: out = [self|mean](bf16) @ WT^T + b ----------------
// Block: 128 rows x COUT cols, 4 waves; wave: 32 rows (2 m-tiles of 16).
// K=256 (self 0..127, mean 128..255), 8 steps of mfma_f32_16x16x32_bf16.
// A-frag: uint4/lane from global (16 rows x 64B lines, fully used).
// B-frag: uint4/lane from WT[c][k] (K-contiguous), L1/L2-hot (<=64KB).
template <int COUT, bool RELU, bool FINAL>
__global__ __launch_bounds__(256) void sage_mfma(
    const u16* __restrict__ selfB, const u16* __restrict__ meanB,
    const u16* __restrict__ WT, const float* __restrict__ bias_f,
    void* __restrict__ out, const int* __restrict__ flags) {
    constexpr int NT = COUT / 16;
    const int tid = threadIdx.x;
    const int wave = tid >> 6;
    const int lane = tid & 63;
    const int n16 = lane & 15;
    const int quad = lane >> 4;
    const int rowbase = blockIdx.x * 128 + wave * 32;
    const int bfin = flags[1];

    int ar0 = rowbase + n16;
    int ar1 = rowbase + 16 + n16;
    ar0 = (ar0 < NN) ? ar0 : (NN - 1);
    ar1 = (ar1 < NN) ? ar1 : (NN - 1);

    const u16* aS0 = selfB + (size_t)ar0 * 128 + quad * 8;
    const u16* aS1 = selfB + (size_t)ar1 * 128 + quad * 8;
    const u16* aM0 = meanB + (size_t)ar0 * 128 + quad * 8;
    const u16* aM1 = meanB + (size_t)ar1 * 128 + quad * 8;
    const u16* bp = WT + (size_t)n16 * 256 + quad * 8;

    v4f acc[2][NT];
#pragma unroll
    for (int mt = 0; mt < 2; ++mt)
#pragma unroll
        for (int nt = 0; nt < NT; ++nt) acc[mt][nt] = (v4f)(0.f);

#pragma unroll
    for (int ks = 0; ks < 8; ++ks) {
        const int ko = (ks & 3) * 32;
        U4S8 a0, a1;
        a0.u = *(const uint4*)((ks < 4 ? aS0 : aM0) + ko);
        a1.u = *(const uint4*)((ks < 4 ? aS1 : aM1) + ko);
        U4S8 b[NT];
#pragma unroll
        for (int nt = 0; nt < NT; ++nt)
            b[nt].u = *(const uint4*)(bp + nt * 16 * 256 + ks * 32);
#pragma unroll
        for (int nt = 0; nt < NT; ++nt) {
            acc[0][nt] = __builtin_amdgcn_mfma_f32_16x16x32_bf16(
                a0.s, b[nt].s, acc[0][nt], 0, 0, 0);
            acc[1][nt] = __builtin_amdgcn_mfma_f32_16x16x32_bf16(
                a1.s, b[nt].s, acc[1][nt], 0, 0, 0);
        }
    }

    // epilogue: C/D layout col=lane&15, row=quad*4+reg (verified mapping)
#pragma unroll
    for (int nt = 0; nt < NT; ++nt) {
        const int c = nt * 16 + n16;
        const float bv = bias_f[c];
#pragma unroll
        for (int mt = 0; mt < 2; ++mt) {
#pragma unroll
            for (int r = 0; r < 4; ++r) {
                int row = rowbase + mt * 16 + quad * 4 + r;
                if (row < NN) {
                    float v = acc[mt][nt][r] + bv;
                    if (RELU) v = fmaxf(v, 0.f);
                    if (FINAL && !bfin)
                        ((float*)out)[(size_t)row * COUT + c] = v;
                    else
                        ((u16*)out)[(size_t)row * COUT + c] = f2bf(v);
                }
            }
        }
    }
}

extern "C" void kernel_launch(void* const* d_in, const int* in_sizes, int n_in,
                              void* d_out, int out_size, void* d_ws,
                              size_t ws_size, hipStream_t stream) {
    const void* x = d_in[0];
    const void* ei = d_in[1];
    const void* Wl0 = d_in[2];
    const void* Wr0 = d_in[3];
    const void* b0 = d_in[4];
    const void* Wl1 = d_in[5];
    const void* Wr1 = d_in[6];
    const void* b1 = d_in[7];
    const void* Wl2 = d_in[8];
    const void* Wr2 = d_in[9];
    const void* b2 = d_in[10];

    char* ws = (char*)d_ws;
    size_t o = 0;
    auto alloc = [&](size_t bytes) {
        void* p = ws + o;
        o = (o + bytes + 511) & ~(size_t)511;
        return p;
    };
    int* flags = (int*)alloc(16);
    int* counts = (int*)alloc(NN * 4);
    int* off = (int*)alloc((NN + 1) * 4);
    int* bsums = (int*)alloc(128 * 4);
    int* cursor = (int*)alloc(NN * 4);
    int* ssrc = (int*)alloc((size_t)NE * 4);
    u32* xb = (u32*)alloc((size_t)NN * 64 * 4);     // bf16 x
    u32* meanB = (u32*)alloc((size_t)NN * 64 * 4);  // bf16 mean
    u32* h1 = (u32*)alloc((size_t)NN * 64 * 4);     // bf16 h1
    u32* h2 = (u32*)alloc((size_t)NN * 64 * 4);     // bf16 h2
    u16* WT0 = (u16*)alloc(256 * 128 * 2);
    u16* WT1 = (u16*)alloc(256 * 128 * 2);
    u16* WT2 = (u16*)alloc(256 * 64 * 2);
    float* bf0 = (float*)alloc(128 * 4);
    float* bf1 = (float*)alloc(128 * 4);
    float* bf2_ = (float*)alloc(64 * 4);

    constexpr int NB_SCAN = (NN + 1023) / 1024;  // 98
    constexpr int RB = (NN + 127) / 128;         // 782

    detect_kernel<<<1, 256, 0, stream>>>((const u32*)ei, (const u32*)x, flags);
    conv_x<<<(NN * 64 + 255) / 256, 256, 0, stream>>>(x, flags, xb);
    wt_prep<<<128, 256, 0, stream>>>(Wr0, Wl0, b0, flags, 128, WT0, bf0);
    wt_prep<<<128, 256, 0, stream>>>(Wr1, Wl1, b1, flags, 128, WT1, bf1);
    wt_prep<<<64, 256, 0, stream>>>(Wr2, Wl2, b2, flags, 64, WT2, bf2_);

    zero_counts<<<(NN + 255) / 256, 256, 0, stream>>>(counts);
    count_deg<<<NE / 256, 256, 0, stream>>>(ei, flags, counts);
    scan_block<<<NB_SCAN, 256, 0, stream>>>(counts, off, bsums);
    scan_top<<<1, 64, 0, stream>>>(bsums, NB_SCAN);
    scan_add<<<(NN + 255) / 256, 256, 0, stream>>>(off, bsums, cursor);
    fill_csr<<<NE / 256, 256, 0, stream>>>(ei, flags, cursor, ssrc);

    // layer 0
    gather_mean_b<<<NN / 4, 256, 0, stream>>>(xb, off, ssrc, meanB);
    sage_mfma<128, true, false><<<RB, 256, 0, stream>>>(
        (const u16*)xb, (const u16*)meanB, WT0, bf0, h1, flags);
    // layer 1
    gather_mean_b<<<NN / 4, 256, 0, stream>>>(h1, off, ssrc, meanB);
    sage_mfma<128, true, false><<<RB, 256, 0, stream>>>(
        (const u16*)h1, (const u16*)meanB, WT1, bf1, h2, flags);
    // layer 2
    gather_mean_b<<<NN / 4, 256, 0, stream>>>(h2, off, ssrc, meanB);
    sage_mfma<64, false, true><<<RB, 256, 0, stream>>>(
        (const u16*)h2, (const u16*)meanB, WT2, bf2_, d_out, flags);
}

// Round 5
// 638.825 us; speedup vs baseline: 21.8632x; 1.4329x over previous
//
#include <hip/hip_runtime.h>
#include <stdint.h>

#define NN 100000
#define NE 1600000

typedef unsigned int u32;
typedef unsigned short u16;
typedef short v8s __attribute__((ext_vector_type(8)));
typedef float v4f __attribute__((ext_vector_type(4)));

union U4S8 {
    uint4 u;
    v8s s;
};

__device__ __forceinline__ float bf2f(u16 u) {
    return __uint_as_float(((u32)u) << 16);
}
__device__ __forceinline__ u16 f2bf(float f) {
    u32 u = __float_as_uint(f);
    u = u + 0x7FFFu + ((u >> 16) & 1u);
    return (u16)(u >> 16);
}
__device__ __forceinline__ float lo16(u32 u) { return __uint_as_float(u << 16); }
__device__ __forceinline__ float hi16(u32 u) {
    return __uint_as_float(u & 0xFFFF0000u);
}

// ---------------- dtype detection ----------------
__global__ void detect_kernel(const u32* __restrict__ ei,
                              const u32* __restrict__ x, int* flags) {
    __shared__ int bad64, badbf;
    int t = threadIdx.x;
    if (t == 0) { bad64 = 0; badbf = 0; }
    __syncthreads();
    if (ei[2 * t + 1] != 0u) atomicAdd(&bad64, 1);
    u32 d = x[t];
    u32 e = (d >> 7) & 0xFFu;
    if (e != 0u && (e < 96u || e > 160u)) atomicAdd(&badbf, 1);
    __syncthreads();
    if (t == 0) {
        flags[0] = (bad64 < 16) ? 1 : 0;
        flags[1] = (badbf < 16) ? 1 : 0;
    }
}

__device__ __forceinline__ void load_edge(const void* ei, int e, int is64,
                                          int& s, int& d) {
    if (is64) {
        const long long* p = (const long long*)ei;
        s = (int)p[e];
        d = (int)p[NE + e];
    } else {
        const int* p = (const int*)ei;
        s = p[e];
        d = p[NE + e];
    }
}

// ---------------- prep: x -> bf16 ----------------
__global__ void conv_x(const void* __restrict__ x, const int* __restrict__ flags,
                       u32* __restrict__ xb) {
    int i = blockIdx.x * 256 + threadIdx.x;  // over NN*64 u32-pairs
    if (i >= NN * 64) return;
    u32 o;
    if (flags[1]) {
        o = ((const u32*)x)[i];
    } else {
        float2 v = ((const float2*)x)[i];
        o = ((u32)f2bf(v.y) << 16) | (u32)f2bf(v.x);
    }
    xb[i] = o;
}

// ---------------- prep: WT[c][k] = (k<128?Wr:Wl)[k%128][c], bias->f32 ----------
__global__ void wt_prep(const void* __restrict__ Wr, const void* __restrict__ Wl,
                        const void* __restrict__ bias,
                        const int* __restrict__ flags, int cout,
                        u16* __restrict__ WT, float* __restrict__ bias_f) {
    int t = blockIdx.x * 256 + threadIdx.x;
    if (t < 256 * cout) {
        int k = t / cout, c = t % cout;
        const void* W = (k < 128) ? Wr : Wl;
        int kk = k & 127;
        float v;
        if (flags[1])
            v = bf2f(((const u16*)W)[kk * cout + c]);
        else
            v = ((const float*)W)[kk * cout + c];
        WT[c * 256 + k] = f2bf(v);
    }
    if (t < cout) {
        bias_f[t] =
            flags[1] ? bf2f(((const u16*)bias)[t]) : ((const float*)bias)[t];
    }
}

// ---------------- CSR build ----------------
__global__ void zero_counts(int* counts) {
    int i = blockIdx.x * 256 + threadIdx.x;
    if (i < NN) counts[i] = 0;
}

__global__ void count_deg(const void* ei, const int* __restrict__ flags,
                          int* __restrict__ counts) {
    int e = blockIdx.x * 256 + threadIdx.x;
    if (e >= NE) return;
    int s, d;
    load_edge(ei, e, flags[0], s, d);
    atomicAdd(&counts[d], 1);
}

__global__ void scan_block(const int* __restrict__ counts,
                           int* __restrict__ off, int* __restrict__ bsums) {
    __shared__ int sS[256];
    int t = threadIdx.x;
    int base = blockIdx.x * 1024 + t * 4;
    int c[4];
#pragma unroll
    for (int i = 0; i < 4; ++i) c[i] = (base + i < NN) ? counts[base + i] : 0;
    int s = c[0] + c[1] + c[2] + c[3];
    sS[t] = s;
    __syncthreads();
    for (int dlt = 1; dlt < 256; dlt <<= 1) {
        int v = (t >= dlt) ? sS[t - dlt] : 0;
        __syncthreads();
        sS[t] += v;
        __syncthreads();
    }
    int run = sS[t] - s;
    if (t == 255) bsums[blockIdx.x] = sS[255];
#pragma unroll
    for (int i = 0; i < 4; ++i) {
        if (base + i < NN) off[base + i] = run;
        run += c[i];
    }
}

__global__ void scan_top(int* bsums, int nb) {
    if (threadIdx.x == 0 && blockIdx.x == 0) {
        int run = 0;
        for (int i = 0; i < nb; ++i) {
            int v = bsums[i];
            bsums[i] = run;
            run += v;
        }
    }
}

__global__ void scan_add(int* __restrict__ off, const int* __restrict__ bsums,
                         int* __restrict__ cursor) {
    int i = blockIdx.x * 256 + threadIdx.x;
    if (i < NN) {
        int v = off[i] + bsums[i >> 10];
        off[i] = v;
        cursor[i] = v;
    }
    if (i == 0) off[NN] = NE;
}

__global__ void fill_csr(const void* ei, const int* __restrict__ flags,
                         int* __restrict__ cursor, int* __restrict__ ssrc) {
    int e = blockIdx.x * 256 + threadIdx.x;
    if (e >= NE) return;
    int s, d;
    load_edge(ei, e, flags[0], s, d);
    int pos = atomicAdd(&cursor[d], 1);
    ssrc[pos] = s;
}

// ---------------- mean aggregation (gather, bf16 in/out) ----------------
// one wave per node. MLP: the wave loads up to 64 neighbor ids with ONE
// coalesced load (lane-strided), broadcasts via __shfl, and issues 16
// independent 256B feature gathers per batch (masked tail, idx=0 safe).
__global__ __launch_bounds__(256) void gather_mean_b(
    const u32* __restrict__ feat, const int* __restrict__ off,
    const int* __restrict__ ssrc, u32* __restrict__ meanB) {
    int node = blockIdx.x * 4 + (threadIdx.x >> 6);
    int lane = threadIdx.x & 63;
    int o0 = off[node], o1 = off[node + 1];
    int cnt = o1 - o0;
    float a0 = 0.f, a1 = 0.f;
    for (int base = 0; base < cnt; base += 64) {
        int lim = cnt - base;
        if (lim > 64) lim = 64;
        int myidx = (lane < lim) ? ssrc[o0 + base + lane] : 0;
        for (int j = 0; j < lim; j += 16) {
            u32 uu[16];
#pragma unroll
            for (int q = 0; q < 16; ++q) {
                int idx = __shfl(myidx, (j + q) & 63);
                uu[q] = feat[(size_t)idx * 64 + lane];
            }
#pragma unroll
            for (int q = 0; q < 16; ++q) {
                if (j + q < lim) {
                    a0 += lo16(uu[q]);
                    a1 += hi16(uu[q]);
                }
            }
        }
    }
    float inv = 1.0f / (float)(cnt > 0 ? cnt : 1);
    meanB[node * 64 + lane] =
        ((u32)f2bf(a1 * inv) << 16) | (u32)f2bf(a0 * inv);
}

// ---------------- MFMA GEMM: out = [self|mean](bf16) @ WT^T + b ----------------
// Block: 128 rows x COUT cols, 4 waves; wave: 32 rows (2 m-tiles of 16).
// K=256 (self 0..127, mean 128..255), 8 steps of mfma_f32_16x16x32_bf16.
// A-frag: uint4/lane from global (16 rows x 64B lines, fully used).
// B-frag: uint4/lane from WT[c][k] (K-contiguous), L1/L2-hot (<=64KB).
template <int COUT, bool RELU, bool FINAL>
__global__ __launch_bounds__(256) void sage_mfma(
    const u16* __restrict__ selfB, const u16* __restrict__ meanB,
    const u16* __restrict__ WT, const float* __restrict__ bias_f,
    void* __restrict__ out, const int* __restrict__ flags) {
    constexpr int NT = COUT / 16;
    const int tid = threadIdx.x;
    const int wave = tid >> 6;
    const int lane = tid & 63;
    const int n16 = lane & 15;
    const int quad = lane >> 4;
    const int rowbase = blockIdx.x * 128 + wave * 32;
    const int bfin = flags[1];

    int ar0 = rowbase + n16;
    int ar1 = rowbase + 16 + n16;
    ar0 = (ar0 < NN) ? ar0 : (NN - 1);
    ar1 = (ar1 < NN) ? ar1 : (NN - 1);

    const u16* aS0 = selfB + (size_t)ar0 * 128 + quad * 8;
    const u16* aS1 = selfB + (size_t)ar1 * 128 + quad * 8;
    const u16* aM0 = meanB + (size_t)ar0 * 128 + quad * 8;
    const u16* aM1 = meanB + (size_t)ar1 * 128 + quad * 8;
    const u16* bp = WT + (size_t)n16 * 256 + quad * 8;

    v4f acc[2][NT];
#pragma unroll
    for (int mt = 0; mt < 2; ++mt)
#pragma unroll
        for (int nt = 0; nt < NT; ++nt) acc[mt][nt] = (v4f)(0.f);

#pragma unroll
    for (int ks = 0; ks < 8; ++ks) {
        const int ko = (ks & 3) * 32;
        U4S8 a0, a1;
        a0.u = *(const uint4*)((ks < 4 ? aS0 : aM0) + ko);
        a1.u = *(const uint4*)((ks < 4 ? aS1 : aM1) + ko);
        U4S8 b[NT];
#pragma unroll
        for (int nt = 0; nt < NT; ++nt)
            b[nt].u = *(const uint4*)(bp + nt * 16 * 256 + ks * 32);
#pragma unroll
        for (int nt = 0; nt < NT; ++nt) {
            acc[0][nt] = __builtin_amdgcn_mfma_f32_16x16x32_bf16(
                a0.s, b[nt].s, acc[0][nt], 0, 0, 0);
            acc[1][nt] = __builtin_amdgcn_mfma_f32_16x16x32_bf16(
                a1.s, b[nt].s, acc[1][nt], 0, 0, 0);
        }
    }

    // epilogue: C/D layout col=lane&15, row=quad*4+reg (verified mapping)
#pragma unroll
    for (int nt = 0; nt < NT; ++nt) {
        const int c = nt * 16 + n16;
        const float bv = bias_f[c];
#pragma unroll
        for (int mt = 0; mt < 2; ++mt) {
#pragma unroll
            for (int r = 0; r < 4; ++r) {
                int row = rowbase + mt * 16 + quad * 4 + r;
                if (row < NN) {
                    float v = acc[mt][nt][r] + bv;
                    if (RELU) v = fmaxf(v, 0.f);
                    if (FINAL && !bfin)
                        ((float*)out)[(size_t)row * COUT + c] = v;
                    else
                        ((u16*)out)[(size_t)row * COUT + c] = f2bf(v);
                }
            }
        }
    }
}

extern "C" void kernel_launch(void* const* d_in, const int* in_sizes, int n_in,
                              void* d_out, int out_size, void* d_ws,
                              size_t ws_size, hipStream_t stream) {
    const void* x = d_in[0];
    const void* ei = d_in[1];
    const void* Wl0 = d_in[2];
    const void* Wr0 = d_in[3];
    const void* b0 = d_in[4];
    const void* Wl1 = d_in[5];
    const void* Wr1 = d_in[6];
    const void* b1 = d_in[7];
    const void* Wl2 = d_in[8];
    const void* Wr2 = d_in[9];
    const void* b2 = d_in[10];

    char* ws = (char*)d_ws;
    size_t o = 0;
    auto alloc = [&](size_t bytes) {
        void* p = ws + o;
        o = (o + bytes + 511) & ~(size_t)511;
        return p;
    };
    int* flags = (int*)alloc(16);
    int* counts = (int*)alloc(NN * 4);
    int* off = (int*)alloc((NN + 1) * 4);
    int* bsums = (int*)alloc(128 * 4);
    int* cursor = (int*)alloc(NN * 4);
    int* ssrc = (int*)alloc((size_t)NE * 4);
    u32* xb = (u32*)alloc((size_t)NN * 64 * 4);     // bf16 x
    u32* meanB = (u32*)alloc((size_t)NN * 64 * 4);  // bf16 mean
    u32* h1 = (u32*)alloc((size_t)NN * 64 * 4);     // bf16 h1
    u32* h2 = (u32*)alloc((size_t)NN * 64 * 4);     // bf16 h2
    u16* WT0 = (u16*)alloc(256 * 128 * 2);
    u16* WT1 = (u16*)alloc(256 * 128 * 2);
    u16* WT2 = (u16*)alloc(256 * 64 * 2);
    float* bf0 = (float*)alloc(128 * 4);
    float* bf1 = (float*)alloc(128 * 4);
    float* bf2_ = (float*)alloc(64 * 4);

    constexpr int NB_SCAN = (NN + 1023) / 1024;  // 98
    constexpr int RB = (NN + 127) / 128;         // 782

    detect_kernel<<<1, 256, 0, stream>>>((const u32*)ei, (const u32*)x, flags);
    conv_x<<<(NN * 64 + 255) / 256, 256, 0, stream>>>(x, flags, xb);
    wt_prep<<<128, 256, 0, stream>>>(Wr0, Wl0, b0, flags, 128, WT0, bf0);
    wt_prep<<<128, 256, 0, stream>>>(Wr1, Wl1, b1, flags, 128, WT1, bf1);
    wt_prep<<<64, 256, 0, stream>>>(Wr2, Wl2, b2, flags, 64, WT2, bf2_);

    zero_counts<<<(NN + 255) / 256, 256, 0, stream>>>(counts);
    count_deg<<<NE / 256, 256, 0, stream>>>(ei, flags, counts);
    scan_block<<<NB_SCAN, 256, 0, stream>>>(counts, off, bsums);
    scan_top<<<1, 64, 0, stream>>>(bsums, NB_SCAN);
    scan_add<<<(NN + 255) / 256, 256, 0, stream>>>(off, bsums, cursor);
    fill_csr<<<NE / 256, 256, 0, stream>>>(ei, flags, cursor, ssrc);

    // layer 0
    gather_mean_b<<<NN / 4, 256, 0, stream>>>(xb, off, ssrc, meanB);
    sage_mfma<128, true, false><<<RB, 256, 0, stream>>>(
        (const u16*)xb, (const u16*)meanB, WT0, bf0, h1, flags);
    // layer 1
    gather_mean_b<<<NN / 4, 256, 0, stream>>>(h1, off, ssrc, meanB);
    sage_mfma<128, true, false><<<RB, 256, 0, stream>>>(
        (const u16*)h1, (const u16*)meanB, WT1, bf1, h2, flags);
    // layer 2
    gather_mean_b<<<NN / 4, 256, 0, stream>>>(h2, off, ssrc, meanB);
    sage_mfma<64, false, true><<<RB, 256, 0, stream>>>(
        (const u16*)h2, (const u16*)meanB, WT2, bf2_, d_out, flags);
}

// Round 6
// 498.903 us; speedup vs baseline: 27.9950x; 1.2805x over previous
//
#include <hip/hip_runtime.h>
#include <stdint.h>

#define NN 100000
#define NE 1600000
#define NBUK 782   // ceil(NN/128)
#define G 256      // pass-1/2 blocks
#define CHUNK 6250 // NE / G

typedef unsigned int u32;
typedef unsigned short u16;
typedef short v8s __attribute__((ext_vector_type(8)));
typedef float v4f __attribute__((ext_vector_type(4)));

union U4S8 {
    uint4 u;
    v8s s;
};

__device__ __forceinline__ float bf2f(u16 u) {
    return __uint_as_float(((u32)u) << 16);
}
__device__ __forceinline__ u16 f2bf(float f) {
    u32 u = __float_as_uint(f);
    u = u + 0x7FFFu + ((u >> 16) & 1u);
    return (u16)(u >> 16);
}
__device__ __forceinline__ float lo16(u32 u) { return __uint_as_float(u << 16); }
__device__ __forceinline__ float hi16(u32 u) {
    return __uint_as_float(u & 0xFFFF0000u);
}

// ---------------- dtype detection ----------------
__global__ void detect_kernel(const u32* __restrict__ ei,
                              const u32* __restrict__ x, int* flags) {
    __shared__ int bad64, badbf;
    int t = threadIdx.x;
    if (t == 0) { bad64 = 0; badbf = 0; }
    __syncthreads();
    if (ei[2 * t + 1] != 0u) atomicAdd(&bad64, 1);
    u32 d = x[t];
    u32 e = (d >> 7) & 0xFFu;
    if (e != 0u && (e < 96u || e > 160u)) atomicAdd(&badbf, 1);
    __syncthreads();
    if (t == 0) {
        flags[0] = (bad64 < 16) ? 1 : 0;
        flags[1] = (badbf < 16) ? 1 : 0;
    }
}

// ---------------- prep: x -> bf16 ----------------
__global__ void conv_x(const void* __restrict__ x, const int* __restrict__ flags,
                       u32* __restrict__ xb) {
    int i = blockIdx.x * 256 + threadIdx.x;
    if (i >= NN * 64) return;
    u32 o;
    if (flags[1]) {
        o = ((const u32*)x)[i];
    } else {
        float2 v = ((const float2*)x)[i];
        o = ((u32)f2bf(v.y) << 16) | (u32)f2bf(v.x);
    }
    xb[i] = o;
}

// ---------------- prep: WT[c][k] = (k<128?Wr:Wl)[k%128][c], bias->f32 ----------
__global__ void wt_prep(const void* __restrict__ Wr, const void* __restrict__ Wl,
                        const void* __restrict__ bias,
                        const int* __restrict__ flags, int cout,
                        u16* __restrict__ WT, float* __restrict__ bias_f) {
    int t = blockIdx.x * 256 + threadIdx.x;
    if (t < 256 * cout) {
        int k = t / cout, c = t % cout;
        const void* W = (k < 128) ? Wr : Wl;
        int kk = k & 127;
        float v;
        if (flags[1])
            v = bf2f(((const u16*)W)[kk * cout + c]);
        else
            v = ((const float*)W)[kk * cout + c];
        WT[c * 256 + k] = f2bf(v);
    }
    if (t < cout) {
        bias_f[t] =
            flags[1] ? bf2f(((const u16*)bias)[t]) : ((const float*)bias)[t];
    }
}

// ---------------- bucketed CSR build ----------------
__global__ void zero_arr(int* p, int n) {
    int i = blockIdx.x * 256 + threadIdx.x;
    if (i < n) p[i] = 0;
}

// P1: per-block coarse histogram of dst>>7 into hist[b*G + g]
__global__ __launch_bounds__(256) void p1_hist(const void* __restrict__ ei,
                                               const int* __restrict__ flags,
                                               int* __restrict__ hist) {
    __shared__ int h[NBUK];
    int g = blockIdx.x, t = threadIdx.x;
    for (int b = t; b < NBUK; b += 256) h[b] = 0;
    __syncthreads();
    int e0 = g * CHUNK;
    int e1 = e0 + CHUNK;
    const int* p = (const int*)ei;
    if (flags[0]) {
        for (int e = e0 + t; e < e1; e += 256)
            atomicAdd(&h[p[2 * (NE + e)] >> 7], 1);
    } else {
        for (int e = e0 + t; e < e1; e += 256)
            atomicAdd(&h[p[NE + e] >> 7], 1);
    }
    __syncthreads();
    for (int b = t; b < NBUK; b += 256) hist[b * G + g] = h[b];
}

// generic scan: 1024 elements per block (4/thread)
__global__ void scan_block_g(const int* __restrict__ in, int* __restrict__ out,
                             int* __restrict__ bsums, int n) {
    __shared__ int sS[256];
    int t = threadIdx.x;
    int base = blockIdx.x * 1024 + t * 4;
    int c[4];
#pragma unroll
    for (int i = 0; i < 4; ++i) c[i] = (base + i < n) ? in[base + i] : 0;
    int s = c[0] + c[1] + c[2] + c[3];
    sS[t] = s;
    __syncthreads();
    for (int dlt = 1; dlt < 256; dlt <<= 1) {
        int v = (t >= dlt) ? sS[t - dlt] : 0;
        __syncthreads();
        sS[t] += v;
        __syncthreads();
    }
    int run = sS[t] - s;
    if (t == 255) bsums[blockIdx.x] = sS[255];
#pragma unroll
    for (int i = 0; i < 4; ++i) {
        if (base + i < n) out[base + i] = run;
        run += c[i];
    }
}

// single-block parallel exclusive scan of bsums (nb <= 256)
__global__ void scan_top_g(int* bsums, int nb) {
    __shared__ int sS[256];
    int t = threadIdx.x;
    int v = (t < nb) ? bsums[t] : 0;
    sS[t] = v;
    __syncthreads();
    for (int d = 1; d < 256; d <<= 1) {
        int u = (t >= d) ? sS[t - d] : 0;
        __syncthreads();
        sS[t] += u;
        __syncthreads();
    }
    if (t < nb) bsums[t] = sS[t] - v;
}

__global__ void scan_add_g(int* __restrict__ out, const int* __restrict__ bsums,
                           int n) {
    int i = blockIdx.x * 256 + threadIdx.x;
    if (i < n) out[i] += bsums[i >> 10];
}

// P2: scatter (src,dst) into bucket-sorted ebuf via LDS cursors
__global__ __launch_bounds__(256) void p2_scatter(const void* __restrict__ ei,
                                                  const int* __restrict__ flags,
                                                  const int* __restrict__ histS,
                                                  int2* __restrict__ ebuf) {
    __shared__ int cur[NBUK];
    int g = blockIdx.x, t = threadIdx.x;
    for (int b = t; b < NBUK; b += 256) cur[b] = histS[b * G + g];
    __syncthreads();
    int e0 = g * CHUNK;
    int e1 = e0 + CHUNK;
    const int* p = (const int*)ei;
    int is64 = flags[0];
    for (int e = e0 + t; e < e1; e += 256) {
        int s, d;
        if (is64) {
            s = p[2 * e];
            d = p[2 * (NE + e)];
        } else {
            s = p[e];
            d = p[NE + e];
        }
        int pos = atomicAdd(&cur[d >> 7], 1);
        ebuf[pos] = make_int2(s, d);
    }
}

// P3: one block per bucket (128 nodes): exact counts, local scan -> off[],
// then scatter src into the bucket's contiguous CSR region.
__global__ __launch_bounds__(256) void p3_build(const int* __restrict__ histS,
                                                const int2* __restrict__ ebuf,
                                                int* __restrict__ off,
                                                int* __restrict__ ssrc) {
    __shared__ int cnt[128], pref[128], cur[128];
    int b = blockIdx.x, t = threadIdx.x;
    int node0 = b << 7;
    int bs = histS[b * G];
    int be = (b == NBUK - 1) ? NE : histS[(b + 1) * G];
    if (t < 128) cnt[t] = 0;
    __syncthreads();
    for (int e = bs + t; e < be; e += 256)
        atomicAdd(&cnt[ebuf[e].y - node0], 1);
    __syncthreads();
    if (t < 128) pref[t] = cnt[t];
    __syncthreads();
    for (int d = 1; d < 128; d <<= 1) {
        int v = 0;
        if (t < 128 && t >= d) v = pref[t - d];
        __syncthreads();
        if (t < 128) pref[t] += v;
        __syncthreads();
    }
    if (t < 128) {
        int ex = pref[t] - cnt[t];  // exclusive prefix
        cur[t] = ex;
        int node = node0 + t;
        if (node < NN) off[node] = bs + ex;
    }
    if (b == NBUK - 1 && t == 0) off[NN] = NE;
    __syncthreads();
    for (int e = bs + t; e < be; e += 256) {
        int2 sd = ebuf[e];
        int pos = atomicAdd(&cur[sd.y - node0], 1);
        ssrc[bs + pos] = sd.x;
    }
}

// ---------------- mean aggregation (gather, bf16 in/out) ----------------
__global__ __launch_bounds__(256) void gather_mean_b(
    const u32* __restrict__ feat, const int* __restrict__ off,
    const int* __restrict__ ssrc, u32* __restrict__ meanB) {
    int node = blockIdx.x * 4 + (threadIdx.x >> 6);
    int lane = threadIdx.x & 63;
    int o0 = off[node], o1 = off[node + 1];
    int cnt = o1 - o0;
    float a0 = 0.f, a1 = 0.f;
    for (int base = 0; base < cnt; base += 64) {
        int lim = cnt - base;
        if (lim > 64) lim = 64;
        int myidx = (lane < lim) ? ssrc[o0 + base + lane] : 0;
        for (int j = 0; j < lim; j += 16) {
            u32 uu[16];
#pragma unroll
            for (int q = 0; q < 16; ++q) {
                int idx = __shfl(myidx, (j + q) & 63);
                uu[q] = feat[(size_t)idx * 64 + lane];
            }
#pragma unroll
            for (int q = 0; q < 16; ++q) {
                if (j + q < lim) {
                    a0 += lo16(uu[q]);
                    a1 += hi16(uu[q]);
                }
            }
        }
    }
    float inv = 1.0f / (float)(cnt > 0 ? cnt : 1);
    meanB[node * 64 + lane] =
        ((u32)f2bf(a1 * inv) << 16) | (u32)f2bf(a0 * inv);
}

// ---------------- MFMA GEMM: out = [self|mean](bf16) @ WT^T + b ----------------
template <int COUT, bool RELU, bool FINAL>
__global__ __launch_bounds__(256) void sage_mfma(
    const u16* __restrict__ selfB, const u16* __restrict__ meanB,
    const u16* __restrict__ WT, const float* __restrict__ bias_f,
    void* __restrict__ out, const int* __restrict__ flags) {
    constexpr int NT = COUT / 16;
    const int tid = threadIdx.x;
    const int wave = tid >> 6;
    const int lane = tid & 63;
    const int n16 = lane & 15;
    const int quad = lane >> 4;
    const int rowbase = blockIdx.x * 128 + wave * 32;
    const int bfin = flags[1];

    int ar0 = rowbase + n16;
    int ar1 = rowbase + 16 + n16;
    ar0 = (ar0 < NN) ? ar0 : (NN - 1);
    ar1 = (ar1 < NN) ? ar1 : (NN - 1);

    const u16* aS0 = selfB + (size_t)ar0 * 128 + quad * 8;
    const u16* aS1 = selfB + (size_t)ar1 * 128 + quad * 8;
    const u16* aM0 = meanB + (size_t)ar0 * 128 + quad * 8;
    const u16* aM1 = meanB + (size_t)ar1 * 128 + quad * 8;
    const u16* bp = WT + (size_t)n16 * 256 + quad * 8;

    v4f acc[2][NT];
#pragma unroll
    for (int mt = 0; mt < 2; ++mt)
#pragma unroll
        for (int nt = 0; nt < NT; ++nt) acc[mt][nt] = (v4f)(0.f);

#pragma unroll
    for (int ks = 0; ks < 8; ++ks) {
        const int ko = (ks & 3) * 32;
        U4S8 a0, a1;
        a0.u = *(const uint4*)((ks < 4 ? aS0 : aM0) + ko);
        a1.u = *(const uint4*)((ks < 4 ? aS1 : aM1) + ko);
        U4S8 b[NT];
#pragma unroll
        for (int nt = 0; nt < NT; ++nt)
            b[nt].u = *(const uint4*)(bp + nt * 16 * 256 + ks * 32);
#pragma unroll
        for (int nt = 0; nt < NT; ++nt) {
            acc[0][nt] = __builtin_amdgcn_mfma_f32_16x16x32_bf16(
                a0.s, b[nt].s, acc[0][nt], 0, 0, 0);
            acc[1][nt] = __builtin_amdgcn_mfma_f32_16x16x32_bf16(
                a1.s, b[nt].s, acc[1][nt], 0, 0, 0);
        }
    }

#pragma unroll
    for (int nt = 0; nt < NT; ++nt) {
        const int c = nt * 16 + n16;
        const float bv = bias_f[c];
#pragma unroll
        for (int mt = 0; mt < 2; ++mt) {
#pragma unroll
            for (int r = 0; r < 4; ++r) {
                int row = rowbase + mt * 16 + quad * 4 + r;
                if (row < NN) {
                    float v = acc[mt][nt][r] + bv;
                    if (RELU) v = fmaxf(v, 0.f);
                    if (FINAL && !bfin)
                        ((float*)out)[(size_t)row * COUT + c] = v;
                    else
                        ((u16*)out)[(size_t)row * COUT + c] = f2bf(v);
                }
            }
        }
    }
}

extern "C" void kernel_launch(void* const* d_in, const int* in_sizes, int n_in,
                              void* d_out, int out_size, void* d_ws,
                              size_t ws_size, hipStream_t stream) {
    const void* x = d_in[0];
    const void* ei = d_in[1];
    const void* Wl0 = d_in[2];
    const void* Wr0 = d_in[3];
    const void* b0 = d_in[4];
    const void* Wl1 = d_in[5];
    const void* Wr1 = d_in[6];
    const void* b1 = d_in[7];
    const void* Wl2 = d_in[8];
    const void* Wr2 = d_in[9];
    const void* b2 = d_in[10];

    char* ws = (char*)d_ws;
    size_t o = 0;
    auto alloc = [&](size_t bytes) {
        void* p = ws + o;
        o = (o + bytes + 511) & ~(size_t)511;
        return p;
    };
    int* flags = (int*)alloc(16);
    int* hist = (int*)alloc((size_t)NBUK * G * 4);  // 200192 ints
    int* bsums = (int*)alloc(256 * 4);
    int* off = (int*)alloc((NN + 1) * 4);
    int* ssrc = (int*)alloc((size_t)NE * 4);
    int2* ebuf = (int2*)alloc((size_t)NE * 8);
    u32* xb = (u32*)alloc((size_t)NN * 64 * 4);
    u32* meanB = (u32*)alloc((size_t)NN * 64 * 4);
    u32* h1 = (u32*)alloc((size_t)NN * 64 * 4);
    u32* h2 = (u32*)alloc((size_t)NN * 64 * 4);
    u16* WT0 = (u16*)alloc(256 * 128 * 2);
    u16* WT1 = (u16*)alloc(256 * 128 * 2);
    u16* WT2 = (u16*)alloc(256 * 64 * 2);
    float* bf0 = (float*)alloc(128 * 4);
    float* bf1 = (float*)alloc(128 * 4);
    float* bf2_ = (float*)alloc(64 * 4);

    constexpr int L = NBUK * G;                 // 200192
    constexpr int NBLK = (L + 1023) / 1024;     // 196 (<= 256)
    constexpr int RB = (NN + 127) / 128;        // 782

    detect_kernel<<<1, 256, 0, stream>>>((const u32*)ei, (const u32*)x, flags);
    conv_x<<<(NN * 64 + 255) / 256, 256, 0, stream>>>(x, flags, xb);
    wt_prep<<<128, 256, 0, stream>>>(Wr0, Wl0, b0, flags, 128, WT0, bf0);
    wt_prep<<<128, 256, 0, stream>>>(Wr1, Wl1, b1, flags, 128, WT1, bf1);
    wt_prep<<<64, 256, 0, stream>>>(Wr2, Wl2, b2, flags, 64, WT2, bf2_);

    // bucketed CSR build
    p1_hist<<<G, 256, 0, stream>>>(ei, flags, hist);
    scan_block_g<<<NBLK, 256, 0, stream>>>(hist, hist, bsums, L);
    scan_top_g<<<1, 256, 0, stream>>>(bsums, NBLK);
    scan_add_g<<<(L + 255) / 256, 256, 0, stream>>>(hist, bsums, L);
    p2_scatter<<<G, 256, 0, stream>>>(ei, flags, hist, ebuf);
    p3_build<<<NBUK, 256, 0, stream>>>(hist, ebuf, off, ssrc);

    // layer 0
    gather_mean_b<<<NN / 4, 256, 0, stream>>>(xb, off, ssrc, meanB);
    sage_mfma<128, true, false><<<RB, 256, 0, stream>>>(
        (const u16*)xb, (const u16*)meanB, WT0, bf0, h1, flags);
    // layer 1
    gather_mean_b<<<NN / 4, 256, 0, stream>>>(h1, off, ssrc, meanB);
    sage_mfma<128, true, false><<<RB, 256, 0, stream>>>(
        (const u16*)h1, (const u16*)meanB, WT1, bf1, h2, flags);
    // layer 2
    gather_mean_b<<<NN / 4, 256, 0, stream>>>(h2, off, ssrc, meanB);
    sage_mfma<64, false, true><<<RB, 256, 0, stream>>>(
        (const u16*)h2, (const u16*)meanB, WT2, bf2_, d_out, flags);
}

// Round 7
// 475.180 us; speedup vs baseline: 29.3926x; 1.0499x over previous
//
#include <hip/hip_runtime.h>
#include <stdint.h>

#define NN 100000
#define NE 1600000
#define NBUK 782   // ceil(NN/128)
#define G 256      // pass-1/2 blocks
#define CHUNK 6250 // NE / G

typedef unsigned int u32;
typedef unsigned short u16;
typedef short v8s __attribute__((ext_vector_type(8)));
typedef float v4f __attribute__((ext_vector_type(4)));

union U4S8 {
    uint4 u;
    v8s s;
};

__device__ __forceinline__ float bf2f(u16 u) {
    return __uint_as_float(((u32)u) << 16);
}
__device__ __forceinline__ u16 f2bf(float f) {
    u32 u = __float_as_uint(f);
    u = u + 0x7FFFu + ((u >> 16) & 1u);
    return (u16)(u >> 16);
}
__device__ __forceinline__ float lo16(u32 u) { return __uint_as_float(u << 16); }
__device__ __forceinline__ float hi16(u32 u) {
    return __uint_as_float(u & 0xFFFF0000u);
}

// ---------------- dtype detection ----------------
__global__ void detect_kernel(const u32* __restrict__ ei,
                              const u32* __restrict__ x, int* flags) {
    __shared__ int bad64, badbf;
    int t = threadIdx.x;
    if (t == 0) { bad64 = 0; badbf = 0; }
    __syncthreads();
    if (ei[2 * t + 1] != 0u) atomicAdd(&bad64, 1);
    u32 d = x[t];
    u32 e = (d >> 7) & 0xFFu;
    if (e != 0u && (e < 96u || e > 160u)) atomicAdd(&badbf, 1);
    __syncthreads();
    if (t == 0) {
        flags[0] = (bad64 < 16) ? 1 : 0;
        flags[1] = (badbf < 16) ? 1 : 0;
    }
}

// ---------------- prep: x -> bf16 (+ zero pad row NN of xb,h1,h2) ----------
__global__ void conv_x(const void* __restrict__ x, const int* __restrict__ flags,
                       u32* __restrict__ xb, u32* __restrict__ h1,
                       u32* __restrict__ h2) {
    int i = blockIdx.x * 256 + threadIdx.x;
    if (i >= NN * 64) {
        int p = i - NN * 64;
        if (p < 64) {
            xb[NN * 64 + p] = 0;
            h1[NN * 64 + p] = 0;
            h2[NN * 64 + p] = 0;
        }
        return;
    }
    u32 o;
    if (flags[1]) {
        o = ((const u32*)x)[i];
    } else {
        float2 v = ((const float2*)x)[i];
        o = ((u32)f2bf(v.y) << 16) | (u32)f2bf(v.x);
    }
    xb[i] = o;
}

// ---------------- prep: WT[c][k] = (k<128?Wr:Wl)[k%128][c], bias->f32 ----------
// one launch for all 3 layers: blocks [0,128) L0, [128,256) L1, [256,320) L2
__global__ void wt_prep_all(const void* __restrict__ Wr0,
                            const void* __restrict__ Wl0,
                            const void* __restrict__ b0,
                            const void* __restrict__ Wr1,
                            const void* __restrict__ Wl1,
                            const void* __restrict__ b1,
                            const void* __restrict__ Wr2,
                            const void* __restrict__ Wl2,
                            const void* __restrict__ b2,
                            const int* __restrict__ flags,
                            u16* __restrict__ WT0, float* __restrict__ bf0,
                            u16* __restrict__ WT1, float* __restrict__ bf1,
                            u16* __restrict__ WT2, float* __restrict__ bf2_) {
    const void* Wr;
    const void* Wl;
    const void* bias;
    u16* WT;
    float* bias_f;
    int cout, t;
    if (blockIdx.x < 128) {
        Wr = Wr0; Wl = Wl0; bias = b0; WT = WT0; bias_f = bf0; cout = 128;
        t = blockIdx.x * 256 + threadIdx.x;
    } else if (blockIdx.x < 256) {
        Wr = Wr1; Wl = Wl1; bias = b1; WT = WT1; bias_f = bf1; cout = 128;
        t = (blockIdx.x - 128) * 256 + threadIdx.x;
    } else {
        Wr = Wr2; Wl = Wl2; bias = b2; WT = WT2; bias_f = bf2_; cout = 64;
        t = (blockIdx.x - 256) * 256 + threadIdx.x;
    }
    if (t < 256 * cout) {
        int k = t / cout, c = t % cout;
        const void* W = (k < 128) ? Wr : Wl;
        int kk = k & 127;
        float v;
        if (flags[1])
            v = bf2f(((const u16*)W)[kk * cout + c]);
        else
            v = ((const float*)W)[kk * cout + c];
        WT[c * 256 + k] = f2bf(v);
    }
    if (t < cout) {
        bias_f[t] =
            flags[1] ? bf2f(((const u16*)bias)[t]) : ((const float*)bias)[t];
    }
}

// ---------------- bucketed CSR build ----------------
// P1: per-block coarse histogram of dst>>7 into hist[b*G + g]
__global__ __launch_bounds__(256) void p1_hist(const void* __restrict__ ei,
                                               const int* __restrict__ flags,
                                               int* __restrict__ hist) {
    __shared__ int h[NBUK];
    int g = blockIdx.x, t = threadIdx.x;
    for (int b = t; b < NBUK; b += 256) h[b] = 0;
    __syncthreads();
    int e0 = g * CHUNK;
    int e1 = e0 + CHUNK;
    const int* p = (const int*)ei;
    if (flags[0]) {
        for (int e = e0 + t; e < e1; e += 256)
            atomicAdd(&h[p[2 * (NE + e)] >> 7], 1);
    } else {
        for (int e = e0 + t; e < e1; e += 256)
            atomicAdd(&h[p[NE + e] >> 7], 1);
    }
    __syncthreads();
    for (int b = t; b < NBUK; b += 256) hist[b * G + g] = h[b];
}

// generic scan: 1024 elements per block (4/thread)
__global__ void scan_block_g(const int* __restrict__ in, int* __restrict__ out,
                             int* __restrict__ bsums, int n) {
    __shared__ int sS[256];
    int t = threadIdx.x;
    int base = blockIdx.x * 1024 + t * 4;
    int c[4];
#pragma unroll
    for (int i = 0; i < 4; ++i) c[i] = (base + i < n) ? in[base + i] : 0;
    int s = c[0] + c[1] + c[2] + c[3];
    sS[t] = s;
    __syncthreads();
    for (int dlt = 1; dlt < 256; dlt <<= 1) {
        int v = (t >= dlt) ? sS[t - dlt] : 0;
        __syncthreads();
        sS[t] += v;
        __syncthreads();
    }
    int run = sS[t] - s;
    if (t == 255) bsums[blockIdx.x] = sS[255];
#pragma unroll
    for (int i = 0; i < 4; ++i) {
        if (base + i < n) out[base + i] = run;
        run += c[i];
    }
}

__global__ void scan_top_g(int* bsums, int nb) {
    __shared__ int sS[256];
    int t = threadIdx.x;
    int v = (t < nb) ? bsums[t] : 0;
    sS[t] = v;
    __syncthreads();
    for (int d = 1; d < 256; d <<= 1) {
        int u = (t >= d) ? sS[t - d] : 0;
        __syncthreads();
        sS[t] += u;
        __syncthreads();
    }
    if (t < nb) bsums[t] = sS[t] - v;
}

__global__ void scan_add_g(int* __restrict__ out, const int* __restrict__ bsums,
                           int n) {
    int i = blockIdx.x * 256 + threadIdx.x;
    if (i < n) out[i] += bsums[i >> 10];
}

// P2: scatter (src,dst) into bucket-sorted ebuf via LDS cursors
__global__ __launch_bounds__(256) void p2_scatter(const void* __restrict__ ei,
                                                  const int* __restrict__ flags,
                                                  const int* __restrict__ histS,
                                                  int2* __restrict__ ebuf) {
    __shared__ int cur[NBUK];
    int g = blockIdx.x, t = threadIdx.x;
    for (int b = t; b < NBUK; b += 256) cur[b] = histS[b * G + g];
    __syncthreads();
    int e0 = g * CHUNK;
    int e1 = e0 + CHUNK;
    const int* p = (const int*)ei;
    int is64 = flags[0];
    for (int e = e0 + t; e < e1; e += 256) {
        int s, d;
        if (is64) {
            s = p[2 * e];
            d = p[2 * (NE + e)];
        } else {
            s = p[e];
            d = p[NE + e];
        }
        int pos = atomicAdd(&cur[d >> 7], 1);
        ebuf[pos] = make_int2(s, d);
    }
}

// P3: one block per bucket (128 nodes): exact counts, local scan -> off[],
// then scatter src into the bucket's contiguous CSR region.
__global__ __launch_bounds__(256) void p3_build(const int* __restrict__ histS,
                                                const int2* __restrict__ ebuf,
                                                int* __restrict__ off,
                                                int* __restrict__ ssrc) {
    __shared__ int cnt[128], pref[128], cur[128];
    int b = blockIdx.x, t = threadIdx.x;
    int node0 = b << 7;
    int bs = histS[b * G];
    int be = (b == NBUK - 1) ? NE : histS[(b + 1) * G];
    if (t < 128) cnt[t] = 0;
    __syncthreads();
    for (int e = bs + t; e < be; e += 256)
        atomicAdd(&cnt[ebuf[e].y - node0], 1);
    __syncthreads();
    if (t < 128) pref[t] = cnt[t];
    __syncthreads();
    for (int d = 1; d < 128; d <<= 1) {
        int v = 0;
        if (t < 128 && t >= d) v = pref[t - d];
        __syncthreads();
        if (t < 128) pref[t] += v;
        __syncthreads();
    }
    if (t < 128) {
        int ex = pref[t] - cnt[t];
        cur[t] = ex;
        int node = node0 + t;
        if (node < NN) off[node] = bs + ex;
    }
    if (b == NBUK - 1 && t == 0) off[NN] = NE;
    __syncthreads();
    for (int e = bs + t; e < be; e += 256) {
        int2 sd = ebuf[e];
        int pos = atomicAdd(&cur[sd.y - node0], 1);
        ssrc[bs + pos] = sd.x;
    }
}

// ---------------- mean aggregation (gather, bf16 in/out) ----------------
// one wave per node. Scalarized: o0/o1 via readfirstlane; neighbor ids via one
// coalesced load + readlane (SGPR row base -> SALU addressing); tail slots use
// zero-pad row NN (no per-slot masking). 16 loads in flight per wave.
__global__ __launch_bounds__(256) void gather_mean_b(
    const u32* __restrict__ feat, const int* __restrict__ off,
    const int* __restrict__ ssrc, u32* __restrict__ meanB) {
    int node = blockIdx.x * 4 + (threadIdx.x >> 6);
    int lane = threadIdx.x & 63;
    int o0 = __builtin_amdgcn_readfirstlane(off[node]);
    int o1 = __builtin_amdgcn_readfirstlane(off[node + 1]);
    int cnt = o1 - o0;
    float a0 = 0.f, a1 = 0.f;
    for (int base = 0; base < cnt; base += 64) {
        int lim = cnt - base;
        if (lim > 64) lim = 64;
        int myidx = (lane < lim) ? ssrc[o0 + base + lane] : NN;
        int jb = (lim + 15) & ~15;
        for (int j = 0; j < jb; j += 16) {
            u32 uu[16];
#pragma unroll
            for (int q = 0; q < 16; ++q) {
                int sidx = __builtin_amdgcn_readlane(myidx, j + q);
                uu[q] = feat[(size_t)sidx * 64 + lane];
            }
#pragma unroll
            for (int q = 0; q < 16; ++q) {
                a0 += lo16(uu[q]);
                a1 += hi16(uu[q]);
            }
        }
    }
    float inv = 1.0f / (float)(cnt > 0 ? cnt : 1);
    meanB[node * 64 + lane] =
        ((u32)f2bf(a1 * inv) << 16) | (u32)f2bf(a0 * inv);
}

// ---------------- MFMA GEMM: out = [self|mean](bf16) @ WT^T + b ----------------
template <int COUT, bool RELU, bool FINAL>
__global__ __launch_bounds__(256) void sage_mfma(
    const u16* __restrict__ selfB, const u16* __restrict__ meanB,
    const u16* __restrict__ WT, const float* __restrict__ bias_f,
    void* __restrict__ out, const int* __restrict__ flags) {
    constexpr int NT = COUT / 16;
    const int tid = threadIdx.x;
    const int wave = tid >> 6;
    const int lane = tid & 63;
    const int n16 = lane & 15;
    const int quad = lane >> 4;
    const int rowbase = blockIdx.x * 128 + wave * 32;
    const int bfin = flags[1];

    int ar0 = rowbase + n16;
    int ar1 = rowbase + 16 + n16;
    ar0 = (ar0 < NN) ? ar0 : (NN - 1);
    ar1 = (ar1 < NN) ? ar1 : (NN - 1);

    const u16* aS0 = selfB + (size_t)ar0 * 128 + quad * 8;
    const u16* aS1 = selfB + (size_t)ar1 * 128 + quad * 8;
    const u16* aM0 = meanB + (size_t)ar0 * 128 + quad * 8;
    const u16* aM1 = meanB + (size_t)ar1 * 128 + quad * 8;
    const u16* bp = WT + (size_t)n16 * 256 + quad * 8;

    v4f acc[2][NT];
#pragma unroll
    for (int mt = 0; mt < 2; ++mt)
#pragma unroll
        for (int nt = 0; nt < NT; ++nt) acc[mt][nt] = (v4f)(0.f);

#pragma unroll
    for (int ks = 0; ks < 8; ++ks) {
        const int ko = (ks & 3) * 32;
        U4S8 a0, a1;
        a0.u = *(const uint4*)((ks < 4 ? aS0 : aM0) + ko);
        a1.u = *(const uint4*)((ks < 4 ? aS1 : aM1) + ko);
        U4S8 b[NT];
#pragma unroll
        for (int nt = 0; nt < NT; ++nt)
            b[nt].u = *(const uint4*)(bp + nt * 16 * 256 + ks * 32);
#pragma unroll
        for (int nt = 0; nt < NT; ++nt) {
            acc[0][nt] = __builtin_amdgcn_mfma_f32_16x16x32_bf16(
                a0.s, b[nt].s, acc[0][nt], 0, 0, 0);
            acc[1][nt] = __builtin_amdgcn_mfma_f32_16x16x32_bf16(
                a1.s, b[nt].s, acc[1][nt], 0, 0, 0);
        }
    }

#pragma unroll
    for (int nt = 0; nt < NT; ++nt) {
        const int c = nt * 16 + n16;
        const float bv = bias_f[c];
#pragma unroll
        for (int mt = 0; mt < 2; ++mt) {
#pragma unroll
            for (int r = 0; r < 4; ++r) {
                int row = rowbase + mt * 16 + quad * 4 + r;
                if (row < NN) {
                    float v = acc[mt][nt][r] + bv;
                    if (RELU) v = fmaxf(v, 0.f);
                    if (FINAL && !bfin)
                        ((float*)out)[(size_t)row * COUT + c] = v;
                    else
                        ((u16*)out)[(size_t)row * COUT + c] = f2bf(v);
                }
            }
        }
    }
}

extern "C" void kernel_launch(void* const* d_in, const int* in_sizes, int n_in,
                              void* d_out, int out_size, void* d_ws,
                              size_t ws_size, hipStream_t stream) {
    const void* x = d_in[0];
    const void* ei = d_in[1];
    const void* Wl0 = d_in[2];
    const void* Wr0 = d_in[3];
    const void* b0 = d_in[4];
    const void* Wl1 = d_in[5];
    const void* Wr1 = d_in[6];
    const void* b1 = d_in[7];
    const void* Wl2 = d_in[8];
    const void* Wr2 = d_in[9];
    const void* b2 = d_in[10];

    char* ws = (char*)d_ws;
    size_t o = 0;
    auto alloc = [&](size_t bytes) {
        void* p = ws + o;
        o = (o + bytes + 511) & ~(size_t)511;
        return p;
    };
    int* flags = (int*)alloc(16);
    int* hist = (int*)alloc((size_t)NBUK * G * 4);
    int* bsums = (int*)alloc(256 * 4);
    int* off = (int*)alloc((NN + 1) * 4);
    int* ssrc = (int*)alloc((size_t)NE * 4);
    int2* ebuf = (int2*)alloc((size_t)NE * 8);
    u32* xb = (u32*)alloc((size_t)(NN + 1) * 64 * 4);    // + zero pad row
    u32* meanB = (u32*)alloc((size_t)NN * 64 * 4);
    u32* h1 = (u32*)alloc((size_t)(NN + 1) * 64 * 4);
    u32* h2 = (u32*)alloc((size_t)(NN + 1) * 64 * 4);
    u16* WT0 = (u16*)alloc(256 * 128 * 2);
    u16* WT1 = (u16*)alloc(256 * 128 * 2);
    u16* WT2 = (u16*)alloc(256 * 64 * 2);
    float* bf0 = (float*)alloc(128 * 4);
    float* bf1 = (float*)alloc(128 * 4);
    float* bf2_ = (float*)alloc(64 * 4);

    constexpr int L = NBUK * G;              // 200192
    constexpr int NBLK = (L + 1023) / 1024;  // 196 (<= 256)
    constexpr int RB = (NN + 127) / 128;     // 782

    detect_kernel<<<1, 256, 0, stream>>>((const u32*)ei, (const u32*)x, flags);
    conv_x<<<(NN * 64 + 64 + 255) / 256, 256, 0, stream>>>(x, flags, xb, h1,
                                                           h2);
    wt_prep_all<<<320, 256, 0, stream>>>(Wr0, Wl0, b0, Wr1, Wl1, b1, Wr2, Wl2,
                                         b2, flags, WT0, bf0, WT1, bf1, WT2,
                                         bf2_);

    // bucketed CSR build
    p1_hist<<<G, 256, 0, stream>>>(ei, flags, hist);
    scan_block_g<<<NBLK, 256, 0, stream>>>(hist, hist, bsums, L);
    scan_top_g<<<1, 256, 0, stream>>>(bsums, NBLK);
    scan_add_g<<<(L + 255) / 256, 256, 0, stream>>>(hist, bsums, L);
    p2_scatter<<<G, 256, 0, stream>>>(ei, flags, hist, ebuf);
    p3_build<<<NBUK, 256, 0, stream>>>(hist, ebuf, off, ssrc);

    // layer 0
    gather_mean_b<<<NN / 4, 256, 0, stream>>>(xb, off, ssrc, meanB);
    sage_mfma<128, true, false><<<RB, 256, 0, stream>>>(
        (const u16*)xb, (const u16*)meanB, WT0, bf0, h1, flags);
    // layer 1
    gather_mean_b<<<NN / 4, 256, 0, stream>>>(h1, off, ssrc, meanB);
    sage_mfma<128, true, false><<<RB, 256, 0, stream>>>(
        (const u16*)h1, (const u16*)meanB, WT1, bf1, h2, flags);
    // layer 2
    gather_mean_b<<<NN / 4, 256, 0, stream>>>(h2, off, ssrc, meanB);
    sage_mfma<64, false, true><<<RB, 256, 0, stream>>>(
        (const u16*)h2, (const u16*)meanB, WT2, bf2_, d_out, flags);
}